// Round 3
// baseline (22.464 us; speedup 1.0000x reference)
//
#include <hip/hip_runtime.h>
#include <math.h>

#define N_PTS 1000000
#define M_COMP 64

typedef float v2f __attribute__((ext_vector_type(2)));

// ---------------------------------------------------------------------------
// Kernel 1: per-component coefficients (64 threads, 1 wave).
// s_ij = K_ij + wlog_j is a quadratic polynomial in (x0,x1):
//   s = -g00*x0^2 - 2*g01*x0*x1 - g11*x1^2 + 2*Gmu0*x0 + 2*Gmu1*x1 + (wlog - mu^T G mu)
// All coefficients are pre-scaled by log2(e) so the main kernel can use the
// native exp2 (v_exp_f32) directly.
// Layout in ws: SoA coef[k][64], k = 0..5 -> uniform-index loads batch into
// s_load_dwordx8 in the main kernel.
// ---------------------------------------------------------------------------
__global__ __launch_bounds__(64) void gm_coef(
    const float* __restrict__ mu,   // (64,2)
    const float* __restrict__ A,    // (64,2,2)
    const float* __restrict__ w,    // (64,1)
    float* __restrict__ coef)       // (6,64) in d_ws
{
    const int j = threadIdx.x;  // 0..63, one component per lane
    const float a00 = A[j*4+0], a01 = A[j*4+1], a10 = A[j*4+2], a11 = A[j*4+3];
    // gamma = A A^T / 2 (symmetric 2x2)
    const float g00 = 0.5f*(a00*a00 + a01*a01);
    const float g01 = 0.5f*(a00*a10 + a01*a11);
    const float g11 = 0.5f*(a10*a10 + a11*a11);
    const float det = g00*g11 - g01*g01;

    const float m0 = mu[j*2+0], m1 = mu[j*2+1];
    const float Gmu0 = g00*m0 + g01*m1;
    const float Gmu1 = g01*m0 + g11*m1;
    const float cst  = m0*Gmu0 + m1*Gmu1;   // mu^T G mu

    // wlog_j = log_softmax(w)_j + 0.5*log(det_j); logsumexp over the wave.
    const float wj = w[j];
    float mx = wj;
    #pragma unroll
    for (int mask = 1; mask < 64; mask <<= 1)
        mx = fmaxf(mx, __shfl_xor(mx, mask, 64));
    float se = expf(wj - mx);
    #pragma unroll
    for (int mask = 1; mask < 64; mask <<= 1)
        se += __shfl_xor(se, mask, 64);
    const float lse  = mx + logf(se);
    const float wlog = wj - lse + 0.5f*logf(det);

    const float L2E = 1.4426950408889634f;  // log2(e)
    coef[0*M_COMP+j] = -g00 * L2E;
    coef[1*M_COMP+j] = -(g01+g01) * L2E;
    coef[2*M_COMP+j] = -g11 * L2E;
    coef[3*M_COMP+j] = (Gmu0+Gmu0) * L2E;
    coef[4*M_COMP+j] = (Gmu1+Gmu1) * L2E;
    coef[5*M_COMP+j] = (wlog - cst) * L2E;
}

// ---------------------------------------------------------------------------
// Kernel 2: 2 points per thread. Max-free logsumexp: the quadratic form is
// <= 0 and wlog ~ 0.5, so exp2 args are in [-~50, ~1]*log2e; far components
// flush to 0 harmlessly, the max term never under/overflows in fp32.
// Two accumulators (even/odd j) break the serial dependent add chain.
// ---------------------------------------------------------------------------
__global__ __launch_bounds__(256) void gm_ll(
    const float* __restrict__ sample, // (N,2)
    const float* __restrict__ coef,   // (6,64)
    float* __restrict__ out)          // (N,1)
{
    const int t = blockIdx.x * 256 + threadIdx.x;
    if (t >= N_PTS/2) return;

    const float4 p = reinterpret_cast<const float4*>(sample)[t]; // pts 2t, 2t+1
    const v2f x0  = {p.x, p.z};
    const v2f x1  = {p.y, p.w};
    const v2f xx0 = x0*x0;
    const v2f x01 = x0*x1;
    const v2f xx1 = x1*x1;

    v2f accA = {0.f, 0.f};
    v2f accB = {0.f, 0.f};

    #pragma unroll 4
    for (int j = 0; j < M_COMP; j += 2) {
        {
            const float c0 = coef[0*M_COMP+j], c1 = coef[1*M_COMP+j],
                        c2 = coef[2*M_COMP+j], c3 = coef[3*M_COMP+j],
                        c4 = coef[4*M_COMP+j], c5 = coef[5*M_COMP+j];
            v2f s = {c5, c5};
            s = __builtin_elementwise_fma(x1,  (v2f){c4, c4}, s);
            s = __builtin_elementwise_fma(x0,  (v2f){c3, c3}, s);
            s = __builtin_elementwise_fma(xx1, (v2f){c2, c2}, s);
            s = __builtin_elementwise_fma(x01, (v2f){c1, c1}, s);
            s = __builtin_elementwise_fma(xx0, (v2f){c0, c0}, s);
            accA[0] += __builtin_amdgcn_exp2f(s[0]);
            accA[1] += __builtin_amdgcn_exp2f(s[1]);
        }
        {
            const int k = j + 1;
            const float c0 = coef[0*M_COMP+k], c1 = coef[1*M_COMP+k],
                        c2 = coef[2*M_COMP+k], c3 = coef[3*M_COMP+k],
                        c4 = coef[4*M_COMP+k], c5 = coef[5*M_COMP+k];
            v2f s = {c5, c5};
            s = __builtin_elementwise_fma(x1,  (v2f){c4, c4}, s);
            s = __builtin_elementwise_fma(x0,  (v2f){c3, c3}, s);
            s = __builtin_elementwise_fma(xx1, (v2f){c2, c2}, s);
            s = __builtin_elementwise_fma(x01, (v2f){c1, c1}, s);
            s = __builtin_elementwise_fma(xx0, (v2f){c0, c0}, s);
            accB[0] += __builtin_amdgcn_exp2f(s[0]);
            accB[1] += __builtin_amdgcn_exp2f(s[1]);
        }
    }

    const v2f acc = accA + accB;
    const float LN2 = 0.6931471805599453f;   // ll = log2(sum) * ln(2)
    float2 r;
    r.x = __builtin_amdgcn_logf(acc[0]) * LN2;
    r.y = __builtin_amdgcn_logf(acc[1]) * LN2;
    reinterpret_cast<float2*>(out)[t] = r;
}

extern "C" void kernel_launch(void* const* d_in, const int* in_sizes, int n_in,
                              void* d_out, int out_size, void* d_ws, size_t ws_size,
                              hipStream_t stream)
{
    const float* sample = (const float*)d_in[0];  // (1e6, 2) f32
    const float* mu     = (const float*)d_in[1];  // (64, 2)  f32
    const float* A      = (const float*)d_in[2];  // (64,2,2) f32
    const float* w      = (const float*)d_in[3];  // (64, 1)  f32
    float* out  = (float*)d_out;                  // (1e6, 1) f32
    float* coef = (float*)d_ws;                   // 6*64 floats = 1.5 KB

    gm_coef<<<1, 64, 0, stream>>>(mu, A, w, coef);

    const int threads = N_PTS / 2;                // 2 points per thread
    gm_ll<<<(threads + 255) / 256, 256, 0, stream>>>(sample, coef, out);
}

// Round 4
// 17.800 us; speedup vs baseline: 1.2620x; 1.2620x over previous
//
#include <hip/hip_runtime.h>
#include <math.h>

#define N_PTS 1000000
#define M_COMP 64

typedef float v2f __attribute__((ext_vector_type(2)));

__device__ __forceinline__ float exp2n(float x) { return __builtin_amdgcn_exp2f(x); }
__device__ __forceinline__ float log2n(float x) { return __builtin_amdgcn_logf(x); }

// ---------------------------------------------------------------------------
// Fused kernel.
// Phase 1 (wave 0 of each block): per-component coefficients of the quadratic
//   s_ij = -g00*x0^2 - 2g01*x0*x1 - g11*x1^2 + 2Gmu0*x0 + 2Gmu1*x1
//          + (wlog - mu^T G mu),
// all pre-scaled by log2(e) so the main loop uses native v_exp_f32 directly.
// log_softmax over the 64 weights via 64-lane shfl_xor butterflies with
// native exp2/log2 (no ocml slow paths). SoA layout cf[k][64] in LDS.
//
// Phase 2 (all threads): 4 points per thread as two packed v2f pipelines.
// Components consumed in chunks of 4: six ds_read_b128 broadcasts (uniform
// address -> conflict-free), amortized over 256 points per wave.
// Max-free logsumexp: quadratic form <= 0, wlog ~ 0.5 => exp2 args bounded
// above by ~1.5 and far components flush to 0 harmlessly in fp32.
// ---------------------------------------------------------------------------
__global__ __launch_bounds__(256) void gm_fused(
    const float* __restrict__ sample, // (N,2)
    const float* __restrict__ mu,     // (64,2)
    const float* __restrict__ A,      // (64,2,2)
    const float* __restrict__ w,      // (64,1)
    float* __restrict__ out)          // (N,1)
{
    __shared__ float cf[6 * M_COMP];

    const int tid = threadIdx.x;
    const float L2E = 1.4426950408889634f;
    const float LN2 = 0.6931471805599453f;

    if (tid < 64) {                       // wave 0 exactly
        const int j = tid;
        const float a00 = A[j*4+0], a01 = A[j*4+1], a10 = A[j*4+2], a11 = A[j*4+3];
        const float g00 = 0.5f*(a00*a00 + a01*a01);
        const float g01 = 0.5f*(a00*a10 + a01*a11);
        const float g11 = 0.5f*(a10*a10 + a11*a11);
        const float det = g00*g11 - g01*g01;

        const float m0 = mu[j*2+0], m1 = mu[j*2+1];
        const float Gmu0 = g00*m0 + g01*m1;
        const float Gmu1 = g01*m0 + g11*m1;
        const float cst  = m0*Gmu0 + m1*Gmu1;

        const float wj = w[j];
        float mx = wj;
        #pragma unroll
        for (int m = 1; m < 64; m <<= 1)
            mx = fmaxf(mx, __shfl_xor(mx, m, 64));
        float se = exp2n((wj - mx) * L2E);
        #pragma unroll
        for (int m = 1; m < 64; m <<= 1)
            se += __shfl_xor(se, m, 64);
        const float lse  = mx + log2n(se) * LN2;
        const float wlog = wj - lse + 0.5f * log2n(det) * LN2;

        cf[0*M_COMP+j] = -g00 * L2E;
        cf[1*M_COMP+j] = -(g01+g01) * L2E;
        cf[2*M_COMP+j] = -g11 * L2E;
        cf[3*M_COMP+j] = (Gmu0+Gmu0) * L2E;
        cf[4*M_COMP+j] = (Gmu1+Gmu1) * L2E;
        cf[5*M_COMP+j] = (wlog - cst) * L2E;
    }
    __syncthreads();

    const int t  = blockIdx.x * 256 + tid;   // 4 points per thread
    const int p0 = t * 4;
    const bool ok = p0 < N_PTS;              // N divisible by 4
    const int pl = ok ? p0 : 0;              // clamp OOB threads (no early
                                             // return: keep wave intact)

    const float4* s4 = (const float4*)sample;
    const float4 qa = s4[(pl >> 1) + 0];     // points p0, p0+1
    const float4 qb = s4[(pl >> 1) + 1];     // points p0+2, p0+3

    const v2f ax0 = {qa.x, qa.z}, ax1 = {qa.y, qa.w};
    const v2f bx0 = {qb.x, qb.z}, bx1 = {qb.y, qb.w};
    const v2f axx0 = ax0*ax0, ax01 = ax0*ax1, axx1 = ax1*ax1;
    const v2f bxx0 = bx0*bx0, bx01 = bx0*bx1, bxx1 = bx1*bx1;

    v2f accA = {0.f, 0.f};
    v2f accB = {0.f, 0.f};

    #pragma unroll 4
    for (int jc = 0; jc < M_COMP; jc += 4) {
        const float4 c0 = *(const float4*)&cf[0*M_COMP+jc];
        const float4 c1 = *(const float4*)&cf[1*M_COMP+jc];
        const float4 c2 = *(const float4*)&cf[2*M_COMP+jc];
        const float4 c3 = *(const float4*)&cf[3*M_COMP+jc];
        const float4 c4 = *(const float4*)&cf[4*M_COMP+jc];
        const float4 c5 = *(const float4*)&cf[5*M_COMP+jc];

#define GM_COMP(F)                                                      \
        {                                                               \
            v2f s = {c5.F, c5.F};                                       \
            s = __builtin_elementwise_fma(ax1,  (v2f){c4.F, c4.F}, s);  \
            s = __builtin_elementwise_fma(ax0,  (v2f){c3.F, c3.F}, s);  \
            s = __builtin_elementwise_fma(axx1, (v2f){c2.F, c2.F}, s);  \
            s = __builtin_elementwise_fma(ax01, (v2f){c1.F, c1.F}, s);  \
            s = __builtin_elementwise_fma(axx0, (v2f){c0.F, c0.F}, s);  \
            accA[0] += exp2n(s[0]);                                     \
            accA[1] += exp2n(s[1]);                                     \
            v2f r = {c5.F, c5.F};                                       \
            r = __builtin_elementwise_fma(bx1,  (v2f){c4.F, c4.F}, r);  \
            r = __builtin_elementwise_fma(bx0,  (v2f){c3.F, c3.F}, r);  \
            r = __builtin_elementwise_fma(bxx1, (v2f){c2.F, c2.F}, r);  \
            r = __builtin_elementwise_fma(bx01, (v2f){c1.F, c1.F}, r);  \
            r = __builtin_elementwise_fma(bxx0, (v2f){c0.F, c0.F}, r);  \
            accB[0] += exp2n(r[0]);                                     \
            accB[1] += exp2n(r[1]);                                     \
        }
        GM_COMP(x)
        GM_COMP(y)
        GM_COMP(z)
        GM_COMP(w)
#undef GM_COMP
    }

    if (ok) {
        float4 o;
        o.x = log2n(accA[0]) * LN2;
        o.y = log2n(accA[1]) * LN2;
        o.z = log2n(accB[0]) * LN2;
        o.w = log2n(accB[1]) * LN2;
        *(float4*)&out[p0] = o;
    }
}

extern "C" void kernel_launch(void* const* d_in, const int* in_sizes, int n_in,
                              void* d_out, int out_size, void* d_ws, size_t ws_size,
                              hipStream_t stream)
{
    const float* sample = (const float*)d_in[0];  // (1e6, 2) f32
    const float* mu     = (const float*)d_in[1];  // (64, 2)  f32
    const float* A      = (const float*)d_in[2];  // (64,2,2) f32
    const float* w      = (const float*)d_in[3];  // (64, 1)  f32
    float* out = (float*)d_out;                   // (1e6, 1) f32

    const int threads = N_PTS / 4;                // 4 points per thread
    const int blocks  = (threads + 255) / 256;    // 977
    gm_fused<<<blocks, 256, 0, stream>>>(sample, mu, A, w, out);
}